// Round 10
// baseline (316.475 us; speedup 1.0000x reference)
//
#include <hip/hip_runtime.h>
#include <hip/hip_bf16.h>

#define NN 32768   // nodes
#define BB 64      // graphs
#define MM 512     // nodes per graph
#define HH 4       // heads
#define DD 64      // head dim
#define INF 256    // input features
#define HD 256     // H*D
#define EE 524288  // edges

typedef unsigned short ushort;
typedef unsigned int uint;
typedef short s16x8 __attribute__((ext_vector_type(8)));
typedef ushort u16x8 __attribute__((ext_vector_type(8)));
typedef float f32x4 __attribute__((ext_vector_type(4)));

__device__ __forceinline__ ushort f2bf(float f) {
    uint u = __float_as_uint(f);
    return (ushort)((u + 0x7fffu + ((u >> 16) & 1u)) >> 16);
}
__device__ __forceinline__ float bf2f(ushort u) {
    return __uint_as_float((uint)u << 16);
}
__device__ __forceinline__ uint pkbf(float x, float y) {
    __hip_bfloat162 h = __float22bfloat162_rn(make_float2(x, y));
    return *(uint*)&h;
}

// ---------------------------------------------------------------------------
// K1: convert_w (blocks 0..767) ∪ deg histogram (blocks 768..2815).
// ---------------------------------------------------------------------------
__global__ __launch_bounds__(256) void prep_kernel(
    const float* __restrict__ Wq, const float* __restrict__ Wk,
    const float* __restrict__ Wv, ushort* __restrict__ WT,
    const int* __restrict__ ei, int* __restrict__ deg)
{
    const int bid = blockIdx.x;
    if (bid < 768) {
        const int id = bid * 256 + threadIdx.x;      // 3*65536
        const int mat = id >> 16, rem = id & 65535;
        const int n = rem >> 8, kk = rem & 255;
        const float* W = (mat == 0) ? Wq : (mat == 1) ? Wk : Wv;
        WT[id] = f2bf(W[kk * 256 + n]);              // WT[mat][n][kk]
    } else {
        const int e = (bid - 768) * 256 + threadIdx.x;   // EE total
        atomicAdd(&deg[ei[EE + e]], 1);
    }
}

// ---------------------------------------------------------------------------
// K2: whole-panel qkv GEMM ∪ scan (block 6144). 64x64 tiles, FULL K=256
// panels staged to LDS in one shot (24 x 16B loads/thread, deep MLP, ONE
// barrier), then 32 MFMAs/wave with zero further syncs. 2 blocks/CU
// (67.6 KB LDS), 6144 blocks = ~12 generations -> load/compute overlap
// happens ACROSS blocks instead of inside a barrier-caged K-loop.
// ---------------------------------------------------------------------------
#define AP 264   // LDS pitch (ushorts): 528 B rows, 16B-aligned
__global__ __launch_bounds__(256) void qkv_big(
    const float* __restrict__ Xq, const float* __restrict__ Xs,
    const ushort* __restrict__ WT,
    const float* __restrict__ bq, const float* __restrict__ bk,
    const float* __restrict__ bv,
    ushort* __restrict__ qo, ushort* __restrict__ ko, ushort* __restrict__ vo,
    float* __restrict__ sumsq,
    const int* __restrict__ deg, int* __restrict__ offsets)
{
    __shared__ ushort As[64 * AP];   // 33792 B
    __shared__ ushort Bs[64 * AP];   // 33792 B
    __shared__ float wred[4];
    __shared__ int part[256];

    const int id = blockIdx.x;
    const int t = threadIdx.x;

    if (id == 6144) {   // exclusive scan of deg -> offsets
        const int base = t * 128;
        int s = 0;
        for (int i = 0; i < 128; ++i) s += deg[base + i];
        part[t] = s;
        __syncthreads();
        for (int off = 1; off < 256; off <<= 1) {
            int a = part[t];
            int b2 = (t >= off) ? part[t - off] : 0;
            __syncthreads();
            part[t] = a + b2;
            __syncthreads();
        }
        int run = (t == 0) ? 0 : part[t - 1];
        for (int i = 0; i < 128; ++i) { offsets[base + i] = run; run += deg[base + i]; }
        if (t == 255) offsets[NN] = run;
        return;
    }

    // XCD swizzle: 12 tiles (4 col-tiles x 3 mats) of one row-group adjacent
    const int vv = (id & 7) * 768 + (id >> 3);
    const int rt = vv / 12, rem = vv % 12;
    const int mat = rem >> 2, ct = rem & 3;
    const float* A    = (mat == 0) ? Xq : Xs;
    const ushort* W   = WT + (size_t)mat * 65536;
    const float* bias = (mat == 0) ? bq : (mat == 1) ? bk : bv;
    ushort* C         = (mat == 0) ? qo : (mat == 1) ? ko : vo;
    const int row0 = rt * 64;
    const int col0 = ct * 64;

    const int l = t & 63, w = t >> 6;
    const int fr = l & 15, q4 = l >> 4;

    // ---- stage full panels: thread t -> row t>>2, k-chunk (t&3)*64 ----
    {
        const int srow = t >> 2, sph = (t & 3) * 64;
        const float* ap = &A[(size_t)(row0 + srow) * INF + sph];
        float4 av[16];
#pragma unroll
        for (int i = 0; i < 16; ++i) av[i] = *(const float4*)(ap + 4 * i);
        const ushort* bp = &W[(size_t)(col0 + srow) * INF + sph];
        u16x8 bv8[8];
#pragma unroll
        for (int i = 0; i < 8; ++i) bv8[i] = *(const u16x8*)(bp + 8 * i);
#pragma unroll
        for (int i = 0; i < 8; ++i) {
            uint4 pk = make_uint4(
                pkbf(av[2 * i].x, av[2 * i].y), pkbf(av[2 * i].z, av[2 * i].w),
                pkbf(av[2 * i + 1].x, av[2 * i + 1].y), pkbf(av[2 * i + 1].z, av[2 * i + 1].w));
            *(uint4*)&As[srow * AP + sph + 8 * i] = pk;
        }
#pragma unroll
        for (int i = 0; i < 8; ++i)
            *(u16x8*)&Bs[srow * AP + sph + 8 * i] = bv8[i];
    }
    __syncthreads();   // the ONLY barrier

    // ---- compute: wave w owns rows [16w, 16w+16) x all 64 cols ----
    f32x4 acc[4] = {};
#pragma unroll
    for (int s = 0; s < 8; ++s) {
        const int ko2 = s * 32 + q4 * 8;
        s16x8 af = *(const s16x8*)&As[(16 * w + fr) * AP + ko2];
        s16x8 bf[4];
#pragma unroll
        for (int j = 0; j < 4; ++j)
            bf[j] = *(const s16x8*)&Bs[(16 * j + fr) * AP + ko2];
#pragma unroll
        for (int j = 0; j < 4; ++j)
            acc[j] = __builtin_amdgcn_mfma_f32_16x16x32_bf16(af, bf[j], acc[j], 0, 0, 0);
    }

    // ---- epilogue: bias + sumsq + bf16 stores ----
    float loc = 0.f;
#pragma unroll
    for (int j = 0; j < 4; ++j) {
        const int colg = col0 + 16 * j + fr;
        const float bj = bias[colg];
#pragma unroll
        for (int m = 0; m < 4; ++m) {
            const int rowg = row0 + 16 * w + q4 * 4 + m;
            float cv = acc[j][m] + bj;
            loc += cv * cv;
            C[(size_t)rowg * HD + colg] = f2bf(cv);
        }
    }
    if (mat < 2) {
#pragma unroll
        for (int off = 32; off > 0; off >>= 1) loc += __shfl_down(loc, off, 64);
        if (l == 0) wred[w] = loc;
        __syncthreads();
        if (t == 0) atomicAdd(&sumsq[mat], wred[0] + wred[1] + wred[2] + wred[3]);
    }
}

// ---------------------------------------------------------------------------
// K3: kv_mfma (0..1023) ∪ vbar (1024..3071) ∪ bucket (3072..5119).
// bucket needs only deg/offsets — moved here to shorten the serial chain.
// ---------------------------------------------------------------------------
#define KVP 136
__global__ __launch_bounds__(256) void kv_vbar_bucket(
    const ushort* __restrict__ k16, const ushort* __restrict__ v16,
    float* __restrict__ kv_p, float* __restrict__ ksum_p, float* __restrict__ vsum_p,
    float* __restrict__ vbar,
    const int* __restrict__ ei, const float* __restrict__ ew,
    const int* __restrict__ deg, const int* __restrict__ offsets,
    int* __restrict__ cursor, int2* __restrict__ pairbuf)
{
    __shared__ ushort kT[64 * KVP];
    __shared__ ushort vT[64 * KVP];
    const int bid = blockIdx.x;
    const int t = threadIdx.x;

    if (bid >= 3072) {   // bucket
        const int e = (bid - 3072) * 256 + t;
        const int row = ei[e], col = ei[EE + e];
        const long long prod = (long long)deg[row] * (long long)deg[col];
        float val = 0.f;
        if (prod > 0) val = ew[e] * __frsqrt_rn((float)prod);
        const int pos = atomicAdd(&cursor[col], 1);
        pairbuf[offsets[col] + pos] = make_int2(row, __float_as_int(val));
        return;
    }
    if (bid >= 1024) {   // vbar: mean over heads
        const int idx = (bid - 1024) * 1024 + t * 4;
        const int n = idx >> 6, d0 = idx & 63;
        const ushort* vr = &v16[(size_t)n * HD + d0];
        float4 o;
        float* op = (float*)&o;
#pragma unroll
        for (int j = 0; j < 4; ++j)
            op[j] = 0.25f * (bf2f(vr[j]) + bf2f(vr[64 + j]) +
                             bf2f(vr[128 + j]) + bf2f(vr[192 + j]));
        *(float4*)&vbar[idx] = o;
        return;
    }

    const int h = bid & 3, b = (bid >> 2) & 63, z = bid >> 8;
    const int l = t & 63, w = t >> 6;
    const size_t base = (size_t)b * MM * HD + (size_t)h * DD;
    const int m0 = z * 128;

    {
        const int mat = t >> 7;
        const int u = t & 63;
        const int dhalf = (t >> 6) & 1;
        const int r0 = 2 * u;
        const int d0 = dhalf * 32;
        const ushort* src = mat ? v16 : k16;
        ushort* dst = mat ? vT : kT;
        const ushort* p0 = &src[base + (size_t)(m0 + r0) * HD + d0];
        const ushort* p1 = p0 + HD;
        u16x8 ra[4], rb[4];
#pragma unroll
        for (int i = 0; i < 4; ++i) ra[i] = *(const u16x8*)(p0 + 8 * i);
#pragma unroll
        for (int i = 0; i < 4; ++i) rb[i] = *(const u16x8*)(p1 + 8 * i);
#pragma unroll
        for (int i = 0; i < 4; ++i)
#pragma unroll
            for (int jj = 0; jj < 8; ++jj) {
                const int d = d0 + 8 * i + jj;
                uint pk = (uint)ra[i][jj] | ((uint)rb[i][jj] << 16);
                *(uint*)&dst[d * KVP + r0] = pk;
            }
    }
    __syncthreads();

    const int fr = l & 15, q4 = l >> 4, kg = q4 * 8;
    const int wr2 = (w & 1) * 32, wc2 = (w >> 1) * 32;
    s16x8 ones;
#pragma unroll
    for (int i = 0; i < 8; ++i) ones[i] = (short)0x3F80;

    f32x4 acc[2][2] = {};
    f32x4 aks[2] = {};
    f32x4 avs[2] = {};
#pragma unroll
    for (int s = 0; s < 4; ++s) {
        const int mo = s * 32 + kg;
        s16x8 af[2], bf[2];
        af[0] = *(const s16x8*)&kT[(wr2 + fr) * KVP + mo];
        af[1] = *(const s16x8*)&kT[(wr2 + 16 + fr) * KVP + mo];
        bf[0] = *(const s16x8*)&vT[(wc2 + fr) * KVP + mo];
        bf[1] = *(const s16x8*)&vT[(wc2 + 16 + fr) * KVP + mo];
#pragma unroll
        for (int il = 0; il < 2; ++il)
#pragma unroll
            for (int jl = 0; jl < 2; ++jl)
                acc[il][jl] = __builtin_amdgcn_mfma_f32_16x16x32_bf16(
                    af[il], bf[jl], acc[il][jl], 0, 0, 0);
#pragma unroll
        for (int il = 0; il < 2; ++il)
            aks[il] = __builtin_amdgcn_mfma_f32_16x16x32_bf16(
                af[il], ones, aks[il], 0, 0, 0);
#pragma unroll
        for (int jl = 0; jl < 2; ++jl)
            avs[jl] = __builtin_amdgcn_mfma_f32_16x16x32_bf16(
                ones, bf[jl], avs[jl], 0, 0, 0);
    }

    float* kvb = &kv_p[(((size_t)b * HH + h) * 4 + z) * 4096];
#pragma unroll
    for (int jl = 0; jl < 2; ++jl) {
        const int dv = wc2 + 16 * jl + fr;
#pragma unroll
        for (int il = 0; il < 2; ++il) {
            const int dk = wr2 + 16 * il + q4 * 4;
            *(f32x4*)&kvb[(size_t)dv * 64 + dk] = acc[il][jl];
        }
    }
    float* ksb = &ksum_p[(((size_t)b * HH + h) * 4 + z) * 64];
    float* vsb = &vsum_p[(((size_t)b * HH + h) * 4 + z) * 64];
    if (wc2 == 0 && fr == 0) {
#pragma unroll
        for (int il = 0; il < 2; ++il)
#pragma unroll
            for (int m = 0; m < 4; ++m)
                ksb[wr2 + 16 * il + q4 * 4 + m] = aks[il][m];
    }
    if (wr2 == 0 && l < 16) {
        vsb[wc2 + l]      = avs[0][0];
        vsb[wc2 + 16 + l] = avs[1][0];
    }
}

// ---------------------------------------------------------------------------
// K4: kv_red (0..1023: 4 z-parts -> bf16 kv16) ∪ sumred (1024..1151).
// ---------------------------------------------------------------------------
__global__ __launch_bounds__(256) void red_kernel(
    const float* __restrict__ kv_p, const float* __restrict__ ksum_p,
    const float* __restrict__ vsum_p,
    ushort* __restrict__ kv16, float* __restrict__ ksum_f, float* __restrict__ vsum_f)
{
    const int bid = blockIdx.x;
    const int t = threadIdx.x;

    if (bid < 1024) {
        const int o4 = bid * 1024 + t * 4;
        const int bh = o4 >> 12, off = o4 & 4095;
        const float* p = &kv_p[(size_t)bh * 16384 + off];
        float4 s0 = *(const float4*)p;
        float4 s1 = *(const float4*)(p + 4096);
        float4 s2 = *(const float4*)(p + 8192);
        float4 s3 = *(const float4*)(p + 12288);
        const float r0 = s0.x + s1.x + s2.x + s3.x;
        const float r1 = s0.y + s1.y + s2.y + s3.y;
        const float r2 = s0.z + s1.z + s2.z + s3.z;
        const float r3 = s0.w + s1.w + s2.w + s3.w;
        uint2 pk = make_uint2(pkbf(r0, r1), pkbf(r2, r3));
        *(uint2*)&kv16[(size_t)bh * 4096 + off] = pk;
    } else {
        const int o = (bid - 1024) * 256 + t;    // 0..32767
        const float* src = (o < 16384) ? ksum_p : vsum_p;
        float* dst = (o < 16384) ? ksum_f : vsum_f;
        const int oo = o & 16383;
        const int bh = oo >> 6, d = oo & 63;
        const float* p = &src[(size_t)bh * 256 + d];
        dst[oo] = p[0] + p[64] + p[128] + p[192];
    }
}

// ---------------------------------------------------------------------------
// K5: attn via MFMA. P = q[64x64] x KV^T; KV staged bf16 from kv16.
// ---------------------------------------------------------------------------
#define AKP 72
__global__ __launch_bounds__(256) void attn_mfma(
    const ushort* __restrict__ q16, const ushort* __restrict__ kv16,
    const float* __restrict__ ksum_f, const float* __restrict__ vsum_f,
    const float* __restrict__ sumsq,
    const int* __restrict__ n_nodes, float* __restrict__ out)
{
    const int b = blockIdx.y;
    const int m0 = blockIdx.x * 64;
    const int t = threadIdx.x;
    const int l = t & 63, w = t >> 6;
    const int fr = l & 15, q4 = l >> 4;
    const int wn = (w & 1) * 32, wd = (w >> 1) * 32;

    __shared__ ushort kvbf[64 * AKP];
    __shared__ float ksum_l[64], vsum_l[64], denom_l[64];

    const float nn = (float)n_nodes[b];
    const float inv = 1.0f / (sqrtf(sumsq[0]) * sqrtf(sumsq[1]));
    f32x4 acco[2][2] = {};

    for (int h = 0; h < HH; ++h) {
        __syncthreads();
        {
            const int dv = t >> 2, dk0 = (t & 3) * 16;
            const ushort* kvg = &kv16[((size_t)(b * HH + h)) * 4096 + dv * 64 + dk0];
            *(uint4*)&kvbf[dv * AKP + dk0]     = *(const uint4*)kvg;
            *(uint4*)&kvbf[dv * AKP + dk0 + 8] = *(const uint4*)(kvg + 8);
        }
        if (t >= 64 && t < 128)
            ksum_l[t - 64] = ksum_f[((size_t)(b * HH + h)) * 64 + t - 64];
        else if (t >= 128 && t < 192)
            vsum_l[t - 128] = vsum_f[((size_t)(b * HH + h)) * 64 + t - 128];
        __syncthreads();

        if (t < 64) {
            const ushort* qr = &q16[((size_t)(b * MM + m0 + t)) * HD + h * DD];
            float dsum = 0.f;
#pragma unroll
            for (int c = 0; c < 8; ++c) {
                u16x8 qq = *(const u16x8*)(qr + 8 * c);
#pragma unroll
                for (int j2 = 0; j2 < 8; ++j2)
                    dsum += bf2f(qq[j2]) * ksum_l[8 * c + j2];
            }
            denom_l[t] = nn + inv * dsum;
        }
        __syncthreads();

        f32x4 pacc[2][2] = {};
#pragma unroll
        for (int kx = 0; kx < 2; ++kx) {
            const int k0 = kx * 32;
            s16x8 af[2], bf[2];
#pragma unroll
            for (int il = 0; il < 2; ++il)
                af[il] = *(const s16x8*)&q16[
                    ((size_t)(b * MM + m0 + wn + 16 * il + fr)) * HD + h * DD + k0 + q4 * 8];
#pragma unroll
            for (int jl = 0; jl < 2; ++jl)
                bf[jl] = *(const s16x8*)&kvbf[(wd + 16 * jl + fr) * AKP + k0 + q4 * 8];
#pragma unroll
            for (int il = 0; il < 2; ++il)
#pragma unroll
                for (int jl = 0; jl < 2; ++jl)
                    pacc[il][jl] = __builtin_amdgcn_mfma_f32_16x16x32_bf16(
                        af[il], bf[jl], pacc[il][jl], 0, 0, 0);
        }
#pragma unroll
        for (int il = 0; il < 2; ++il)
#pragma unroll
            for (int m = 0; m < 4; ++m) {
                const float rden = 0.25f / denom_l[wn + 16 * il + q4 * 4 + m];
#pragma unroll
                for (int jl = 0; jl < 2; ++jl) {
                    const int d = wd + 16 * jl + fr;
                    acco[il][jl][m] += (inv * pacc[il][jl][m] + vsum_l[d]) * rden;
                }
            }
    }

#pragma unroll
    for (int il = 0; il < 2; ++il)
#pragma unroll
        for (int m = 0; m < 4; ++m) {
            const size_t node = (size_t)b * MM + m0 + wn + 16 * il + q4 * 4 + m;
#pragma unroll
            for (int jl = 0; jl < 2; ++jl)
                out[node * DD + wd + 16 * jl + fr] = acco[il][jl][m];
        }
}

// ---------------------------------------------------------------------------
// K6: GCN gather (packed pairbuf). out[n] += sum val*vbar[row]. No atomics.
// ---------------------------------------------------------------------------
__global__ __launch_bounds__(256) void gcn_gather(
    const int* __restrict__ offsets, const int2* __restrict__ pairbuf,
    const float* __restrict__ vbar, float* __restrict__ out)
{
    const int t = blockIdx.x * 256 + threadIdx.x;
    const int n = t >> 6, d = t & 63;
    const int s = offsets[n], e = offsets[n + 1];
    float acc = 0.f;
    int i = s;
    for (; i + 4 <= e; i += 4) {
        const int2 p0 = pairbuf[i],     p1 = pairbuf[i + 1];
        const int2 p2 = pairbuf[i + 2], p3 = pairbuf[i + 3];
        acc += __int_as_float(p0.y) * vbar[(size_t)p0.x * DD + d];
        acc += __int_as_float(p1.y) * vbar[(size_t)p1.x * DD + d];
        acc += __int_as_float(p2.y) * vbar[(size_t)p2.x * DD + d];
        acc += __int_as_float(p3.y) * vbar[(size_t)p3.x * DD + d];
    }
    for (; i < e; ++i) {
        const int2 p = pairbuf[i];
        acc += __int_as_float(p.y) * vbar[(size_t)p.x * DD + d];
    }
    out[(size_t)n * DD + d] += acc;
}

// ---------------------------------------------------------------------------
extern "C" void kernel_launch(void* const* d_in, const int* in_sizes, int n_in,
                              void* d_out, int out_size, void* d_ws, size_t ws_size,
                              hipStream_t stream)
{
    (void)in_sizes; (void)n_in; (void)out_size; (void)ws_size;
    const float* Xq = (const float*)d_in[0];
    const float* Xs = (const float*)d_in[1];
    const float* ew = (const float*)d_in[2];
    const float* Wq = (const float*)d_in[3];
    const float* bq = (const float*)d_in[4];
    const float* Wk = (const float*)d_in[5];
    const float* bk = (const float*)d_in[6];
    const float* Wv = (const float*)d_in[7];
    const float* bv = (const float*)d_in[8];
    const int* n_nodes = (const int*)d_in[9];
    const int* ei = (const int*)d_in[10];
    float* out = (float*)d_out;
    float* ws  = (float*)d_ws;

    // workspace layout (float units); q/k/v bf16
    const size_t SZ_QKV   = (size_t)NN * HD / 2;       // 4194304 each
    const size_t OFF_Q    = 0;
    const size_t OFF_K    = SZ_QKV;
    const size_t OFF_V    = SZ_QKV * 2;
    const size_t OFF_SS   = SZ_QKV * 3;                // 16 floats (zeroed)
    const size_t OFF_DEG  = OFF_SS + 16;               // NN ints (zeroed)
    const size_t OFF_CUR  = OFF_DEG + NN;              // NN ints (zeroed)
    const size_t OFF_WT   = OFF_CUR + NN;              // 3*65536 ushorts
    const size_t OFF_KV   = OFF_WT + 3 * 65536 / 2;    // BB*HH*4*4096 parts
    const size_t OFF_KSP  = OFF_KV + (size_t)BB * HH * 4 * 4096;
    const size_t OFF_VSP  = OFF_KSP + (size_t)BB * HH * 4 * 64;
    const size_t OFF_KV16 = OFF_VSP + (size_t)BB * HH * 4 * 64;   // bf16
    const size_t OFF_KSF  = OFF_KV16 + (size_t)BB * HH * 4096 / 2;
    const size_t OFF_VSF  = OFF_KSF + (size_t)BB * HH * 64;
    const size_t OFF_OFFS = OFF_VSF + (size_t)BB * HH * 64;       // NN+1
    const size_t OFF_PAIR = OFF_OFFS + NN + 16;        // EE int2
    const size_t OFF_VBAR = OFF_PAIR + 2 * (size_t)EE; // NN*DD
    // total ≈ 90 MB

    ushort* q16   = (ushort*)(ws + OFF_Q);
    ushort* k16   = (ushort*)(ws + OFF_K);
    ushort* v16   = (ushort*)(ws + OFF_V);
    float* sumsq  = ws + OFF_SS;
    int*   deg    = (int*)(ws + OFF_DEG);
    int*   cursor = (int*)(ws + OFF_CUR);
    ushort* WT    = (ushort*)(ws + OFF_WT);
    float* kv_p   = ws + OFF_KV;
    float* ksum_p = ws + OFF_KSP;
    float* vsum_p = ws + OFF_VSP;
    ushort* kv16  = (ushort*)(ws + OFF_KV16);
    float* ksum_f = ws + OFF_KSF;
    float* vsum_f = ws + OFF_VSF;
    int*   offs   = (int*)(ws + OFF_OFFS);
    int2*  pairb  = (int2*)(ws + OFF_PAIR);
    float* vbar   = ws + OFF_VBAR;

    // zero sumsq + deg + cursor (contiguous)
    hipMemsetAsync(sumsq, 0, (16 + 2 * NN) * sizeof(float), stream);
    prep_kernel<<<2816, 256, 0, stream>>>(Wq, Wk, Wv, WT, ei, deg);
    qkv_big<<<6145, 256, 0, stream>>>(
        Xq, Xs, WT, bq, bk, bv, q16, k16, v16, sumsq, deg, offs);
    kv_vbar_bucket<<<5120, 256, 0, stream>>>(
        k16, v16, kv_p, ksum_p, vsum_p, vbar, ei, ew, deg, offs, cursor, pairb);
    red_kernel<<<1152, 256, 0, stream>>>(
        kv_p, ksum_p, vsum_p, kv16, ksum_f, vsum_f);
    attn_mfma<<<dim3(MM / 64, BB), 256, 0, stream>>>(
        q16, kv16, ksum_f, vsum_f, sumsq, n_nodes, out);
    gcn_gather<<<(NN * DD) / 256, 256, 0, stream>>>(offs, pairb, vbar, out);
}